// Round 1
// baseline (714.211 us; speedup 1.0000x reference)
//
#include <hip/hip_runtime.h>

// Self-attention fwd: q=xWq+bq, k=xWk+bk, v=xWv+bv, P=softmax(causal(qk^T/32)), y=Pv
// B=8 S=2048 DIN=DQ=DV=1024. All GEMMs via bf16 MFMA 16x16x32 (verified layouts):
//   C/D: col=lane&15, row=(lane>>4)*4+reg ;  A/B frag: k=(lane>>4)*8+j, m/n=lane&15
// GEMM operand format: A[M][K] row-major, B as Bt[N][K] row-major (both K-contig).

typedef unsigned short u16;
typedef unsigned int   u32;
typedef float f32x4 __attribute__((ext_vector_type(4)));
typedef short s16x8 __attribute__((ext_vector_type(8)));

__device__ __forceinline__ u16 f2bf(float x) {
  u32 u = __builtin_bit_cast(u32, x);
  u += 0x7fffu + ((u >> 16) & 1u);          // RNE
  return (u16)(u >> 16);
}

__device__ __forceinline__ void gld_lds16(const u16* g, u16* l) {
  __builtin_amdgcn_global_load_lds((const __attribute__((address_space(1))) void*)g,
                                   (__attribute__((address_space(3))) void*)l,
                                   16, 0, 0);
}

// ---- fp32 -> bf16, 4 elems/thread, exact grid ----
__global__ __launch_bounds__(256) void cvt_bf16(const float* __restrict__ in,
                                                u16* __restrict__ out) {
  long i = (long)blockIdx.x * 256 + threadIdx.x;
  float4 v = ((const float4*)in)[i];
  ushort4 o;
  o.x = f2bf(v.x); o.y = f2bf(v.y); o.z = f2bf(v.z); o.w = f2bf(v.w);
  ((ushort4*)out)[i] = o;
}

// ---- W[K][N] fp32 -> Wt[N][K] bf16 ----
__global__ __launch_bounds__(256) void transpose_w(const float* __restrict__ W,
                                                   u16* __restrict__ Wt,
                                                   int K, int N) {
  __shared__ u16 t[32][33];
  int n0 = blockIdx.x * 32, k0 = blockIdx.y * 32;
  int tx = threadIdx.x & 31, ty = threadIdx.x >> 5;
  for (int r = ty; r < 32; r += 8)
    t[r][tx] = f2bf(W[(long)(k0 + r) * N + n0 + tx]);
  __syncthreads();
  for (int r = ty; r < 32; r += 8)
    Wt[(long)(n0 + r) * K + k0 + tx] = t[tx][r];
}

// ---- v[b][S][D] bf16 -> vT[b][D][S] bf16 ----
__global__ __launch_bounds__(256) void transpose_v(const u16* __restrict__ v,
                                                   u16* __restrict__ vt,
                                                   int S, int D) {
  __shared__ u16 t[32][33];
  long b = blockIdx.z;
  const u16* vb = v + b * S * D;
  u16* vtb = vt + b * S * D;
  int d0 = blockIdx.x * 32, s0 = blockIdx.y * 32;
  int tx = threadIdx.x & 31, ty = threadIdx.x >> 5;
  for (int r = ty; r < 32; r += 8)
    t[r][tx] = vb[(long)(s0 + r) * D + d0 + tx];
  __syncthreads();
  for (int r = ty; r < 32; r += 8)
    vtb[(long)(d0 + r) * S + s0 + tx] = t[tx][r];
}

// ---- 128x128x(K) bf16 MFMA GEMM, Bt format. MODE 0: +bias, bf16 out (proj)
//      MODE 1: *scale, f32 out, skip tiles above diagonal (scores, M-tile==N-tile)
//      MODE 2: f32 out, K-loop truncated at diagonal (PV; P is 0 above diag) ----
template <int MODE>
__global__ __launch_bounds__(256, 2)
void gemm_bt(const u16* __restrict__ A, int lda, long sA,
             const u16* __restrict__ Bt, int ldb, long sB,
             void* __restrict__ C, int ldc, long sC,
             int kTiles, float scale, const float* __restrict__ bias) {
  const int bn = blockIdx.x, bm = blockIdx.y, bz = blockIdx.z;
  if (MODE == 1 && bn > bm) return;
  int ktEnd = kTiles;
  if (MODE == 2) { int lim = (bm + 1) * 4; if (lim < ktEnd) ktEnd = lim; }

  const u16* Ab = A + (long)bz * sA;
  const u16* Bb = Bt + (long)bz * sB;

  __shared__ u16 lA[128 * 32];   // [row][k] row-major, rows of 64B
  __shared__ u16 lB[128 * 32];   // [col][k]

  const int tid = threadIdx.x;
  const int lane = tid & 63;
  const int half = lane >> 4, l16 = lane & 15;
  const int wave = tid >> 6;
  const int wm = (wave >> 1) * 64, wn = (wave & 1) * 64;

  f32x4 acc[4][4];
#pragma unroll
  for (int i = 0; i < 4; ++i)
#pragma unroll
    for (int j = 0; j < 4; ++j) { f32x4 z = {0.f, 0.f, 0.f, 0.f}; acc[i][j] = z; }

  // staging: 512 chunks of 16B per tile; chunk c -> row c>>2, kpart c&3.
  // lds dest = chunk*16B: per wave this is uniform base + lane*16 (HW requirement).
  const int c0 = tid, c1 = tid + 256;
  const u16* gA0 = Ab + (long)(bm * 128 + (c0 >> 2)) * lda + (c0 & 3) * 8;
  const u16* gA1 = Ab + (long)(bm * 128 + (c1 >> 2)) * lda + (c1 & 3) * 8;
  const u16* gB0 = Bb + (long)(bn * 128 + (c0 >> 2)) * ldb + (c0 & 3) * 8;
  const u16* gB1 = Bb + (long)(bn * 128 + (c1 >> 2)) * ldb + (c1 & 3) * 8;
  u16* lA0 = &lA[c0 * 8]; u16* lA1 = &lA[c1 * 8];
  u16* lB0 = &lB[c0 * 8]; u16* lB1 = &lB[c1 * 8];

  for (int kt = 0; kt < ktEnd; ++kt) {
    const int k0 = kt * 32;
    gld_lds16(gA0 + k0, lA0);
    gld_lds16(gA1 + k0, lA1);
    gld_lds16(gB0 + k0, lB0);
    gld_lds16(gB1 + k0, lB1);
    __syncthreads();
    s16x8 af[4], bf[4];
#pragma unroll
    for (int mi = 0; mi < 4; ++mi)
      af[mi] = *(const s16x8*)&lA[(wm + mi * 16 + l16) * 32 + half * 8];
#pragma unroll
    for (int ni = 0; ni < 4; ++ni)
      bf[ni] = *(const s16x8*)&lB[(wn + ni * 16 + l16) * 32 + half * 8];
#pragma unroll
    for (int mi = 0; mi < 4; ++mi)
#pragma unroll
      for (int ni = 0; ni < 4; ++ni)
        acc[mi][ni] = __builtin_amdgcn_mfma_f32_16x16x32_bf16(af[mi], bf[ni], acc[mi][ni], 0, 0, 0);
    __syncthreads();
  }

  const int colBase = bn * 128 + wn + l16;
  const int rowBase = bm * 128 + wm + half * 4;
  if (MODE == 0) {
    u16* Cb = (u16*)C + (long)bz * sC;
#pragma unroll
    for (int mi = 0; mi < 4; ++mi)
#pragma unroll
      for (int ni = 0; ni < 4; ++ni) {
        int col = colBase + ni * 16;
        float bv = bias[col];
#pragma unroll
        for (int r = 0; r < 4; ++r) {
          int row = rowBase + mi * 16 + r;
          Cb[(long)row * ldc + col] = f2bf(acc[mi][ni][r] + bv);
        }
      }
  } else {
    float* Cb = (float*)C + (long)bz * sC;
#pragma unroll
    for (int mi = 0; mi < 4; ++mi)
#pragma unroll
      for (int ni = 0; ni < 4; ++ni) {
        int col = colBase + ni * 16;
#pragma unroll
        for (int r = 0; r < 4; ++r) {
          int row = rowBase + mi * 16 + r;
          float val = acc[mi][ni][r];
          Cb[(long)row * ldc + col] = (MODE == 1) ? val * scale : val;
        }
      }
  }
}

// ---- causal row softmax: scores f32 [B*S][S] -> P bf16, zeros above diagonal ----
__global__ __launch_bounds__(256) void softmax_causal(const float* __restrict__ scores,
                                                      u16* __restrict__ P, int S) {
  __shared__ float buf[2048];
  __shared__ float red[4];
  const int tid = threadIdx.x;
  const long row = blockIdx.x;       // b*S + i
  const int i = (int)(row % S);
  const int n = i + 1;               // valid cols
  const float* srow = scores + row * S;
  u16* prow = P + row * S;

  float m = -1e30f;
  for (int j = tid; j < n; j += 256) { float x = srow[j]; buf[j] = x; m = fmaxf(m, x); }
  for (int o = 32; o > 0; o >>= 1) m = fmaxf(m, __shfl_down(m, o));
  if ((tid & 63) == 0) red[tid >> 6] = m;
  __syncthreads();
  m = fmaxf(fmaxf(red[0], red[1]), fmaxf(red[2], red[3]));
  __syncthreads();
  float s = 0.f;
  for (int j = tid; j < n; j += 256) { float e = __expf(buf[j] - m); buf[j] = e; s += e; }
  for (int o = 32; o > 0; o >>= 1) s += __shfl_down(s, o);
  if ((tid & 63) == 0) red[tid >> 6] = s;
  __syncthreads();
  s = red[0] + red[1] + red[2] + red[3];
  float inv = 1.f / s;
  for (int j = tid; j < n; j += 256) prow[j] = f2bf(buf[j] * inv);
  for (int j = n + tid; j < S; j += 256) prow[j] = 0;
}

extern "C" void kernel_launch(void* const* d_in, const int* in_sizes, int n_in,
                              void* d_out, int out_size, void* d_ws, size_t ws_size,
                              hipStream_t stream) {
  const int B = 8, S = 2048, DIN = 1024, DQ = 1024, DV = 1024;
  const long X  = (long)B * S * DIN;   // 16,777,216
  const long WN = (long)DIN * DQ;      //  1,048,576
  // const long SC = (long)B * S * S;  // 33,554,432

  const float* query = (const float*)d_in[0];
  const float* key   = (const float*)d_in[1];
  const float* value = (const float*)d_in[2];
  const float* Wq = (const float*)d_in[3];
  const float* bq = (const float*)d_in[4];
  const float* Wk = (const float*)d_in[5];
  const float* bk = (const float*)d_in[6];
  const float* Wv = (const float*)d_in[7];
  const float* bv = (const float*)d_in[8];
  // d_in[9] = mask: deterministic causal triu -> never read.

  // workspace layout (u16 units). Region A ([0, 4X+3WN)) is reused for fp32
  // scores (134.2MB <= 140.5MB) once x/W/v are dead; region B (q,k) is reused
  // for P once q,k are dead. Total = (7X+3WN)*2 = 241,172,480 bytes.
  u16* w    = (u16*)d_ws;
  u16* xq   = w;
  u16* xk   = w + X;
  u16* xv   = w + 2 * X;
  u16* WqT  = w + 3 * X;
  u16* WkT  = w + 3 * X + WN;
  u16* WvT  = w + 3 * X + 2 * WN;
  u16* vbuf = w + 3 * X + 3 * WN;
  float* scores = (float*)d_ws;        // aliases region A
  const long RB = 4 * X + 3 * WN;
  u16* q  = w + RB;
  u16* k  = w + RB + X;
  u16* P  = w + RB;                    // aliases q,k
  u16* vT = w + RB + 2 * X;

  dim3 blk(256);
  cvt_bf16<<<dim3(X / 1024), blk, 0, stream>>>(query, xq);
  cvt_bf16<<<dim3(X / 1024), blk, 0, stream>>>(key, xk);
  cvt_bf16<<<dim3(X / 1024), blk, 0, stream>>>(value, xv);
  transpose_w<<<dim3(DQ / 32, DIN / 32), blk, 0, stream>>>(Wq, WqT, DIN, DQ);
  transpose_w<<<dim3(DQ / 32, DIN / 32), blk, 0, stream>>>(Wk, WkT, DIN, DQ);
  transpose_w<<<dim3(DV / 32, DIN / 32), blk, 0, stream>>>(Wv, WvT, DIN, DV);

  // projections: M = B*S = 16384, N = 1024, K = 1024
  gemm_bt<0><<<dim3(DQ / 128, (B * S) / 128, 1), blk, 0, stream>>>(
      xq, DIN, 0L, WqT, DIN, 0L, q, DQ, 0L, DIN / 32, 1.f, bq);
  gemm_bt<0><<<dim3(DQ / 128, (B * S) / 128, 1), blk, 0, stream>>>(
      xk, DIN, 0L, WkT, DIN, 0L, k, DQ, 0L, DIN / 32, 1.f, bk);
  gemm_bt<0><<<dim3(DV / 128, (B * S) / 128, 1), blk, 0, stream>>>(
      xv, DIN, 0L, WvT, DIN, 0L, vbuf, DV, 0L, DIN / 32, 1.f, bv);

  transpose_v<<<dim3(DV / 32, S / 32, B), blk, 0, stream>>>(vbuf, vT, S, DV);

  // scores = q k^T / sqrt(DQ): per batch M=N=S, K=DQ; lower-triangular tiles only
  gemm_bt<1><<<dim3(S / 128, S / 128, B), blk, 0, stream>>>(
      q, DQ, (long)S * DQ, k, DQ, (long)S * DQ, scores, S, (long)S * S,
      DQ / 32, 0.03125f, nullptr);

  softmax_causal<<<dim3(B * S), blk, 0, stream>>>(scores, P, S);

  // y = P v: per batch M=S, N=DV, K=S (truncated at diagonal)
  gemm_bt<2><<<dim3(DV / 128, S / 128, B), blk, 0, stream>>>(
      P, S, (long)S * S, vT, S, (long)DV * S, d_out, DV, (long)S * DV,
      S / 32, 1.f, nullptr);
}

// Round 2
// 681.831 us; speedup vs baseline: 1.0475x; 1.0475x over previous
//
#include <hip/hip_runtime.h>

// Self-attention fwd: q=xWq+bq, k=xWk+bk, v=xWv+bv, P=softmax(causal(qk^T/32)), y=Pv
// B=8 S=2048 DIN=DQ=DV=1024. bf16 MFMA 16x16x32 (verified layouts):
//   C/D: col=lane&15, row=(lane>>4)*4+reg ;  A/B frag: k=(lane>>4)*8+j, m/n=lane&15
// GEMM operands: A[M][K] row-major, B as Bt[N][K] row-major (both K-contig).
// LDS uses a 16B-chunk XOR swizzle (slot = row*4 + (kp ^ ((row>>1)&3))) so
// ds_read_b128 fragment reads are 2-way (free) instead of 8-way conflicted,
// while global_load_lds staging stays wave-contiguous (we permute the SOURCE).

typedef unsigned short u16;
typedef unsigned int   u32;
typedef float f32x4 __attribute__((ext_vector_type(4)));
typedef short s16x8 __attribute__((ext_vector_type(8)));

__device__ __forceinline__ u16 f2bf(float x) {
  u32 u = __builtin_bit_cast(u32, x);
  u += 0x7fffu + ((u >> 16) & 1u);          // RNE
  return (u16)(u >> 16);
}

__device__ __forceinline__ void gld_lds16(const u16* g, u16* l) {
  __builtin_amdgcn_global_load_lds((const __attribute__((address_space(1))) void*)g,
                                   (__attribute__((address_space(3))) void*)l,
                                   16, 0, 0);
}

// ---- fp32 -> bf16 for query/key/value in one dispatch (z selects input) ----
__global__ __launch_bounds__(256) void cvt_bf16_3(const float* __restrict__ i0,
                                                  const float* __restrict__ i1,
                                                  const float* __restrict__ i2,
                                                  u16* __restrict__ out, long X) {
  const float* in = blockIdx.y == 0 ? i0 : (blockIdx.y == 1 ? i1 : i2);
  long i = (long)blockIdx.x * 256 + threadIdx.x;
  float4 v = ((const float4*)in)[i];
  ushort4 o;
  o.x = f2bf(v.x); o.y = f2bf(v.y); o.z = f2bf(v.z); o.w = f2bf(v.w);
  ((ushort4*)(out + blockIdx.y * X))[i] = o;
}

// ---- W[K][N] fp32 -> Wt[N][K] bf16, 3 weights in one dispatch ----
__global__ __launch_bounds__(256) void transpose_w3(const float* __restrict__ w0,
                                                    const float* __restrict__ w1,
                                                    const float* __restrict__ w2,
                                                    u16* __restrict__ Wt,
                                                    int K, int N, long WN) {
  __shared__ u16 t[32][33];
  const float* W = blockIdx.z == 0 ? w0 : (blockIdx.z == 1 ? w1 : w2);
  u16* out = Wt + blockIdx.z * WN;
  int n0 = blockIdx.x * 32, k0 = blockIdx.y * 32;
  int tx = threadIdx.x & 31, ty = threadIdx.x >> 5;
  for (int r = ty; r < 32; r += 8)
    t[r][tx] = f2bf(W[(long)(k0 + r) * N + n0 + tx]);
  __syncthreads();
  for (int r = ty; r < 32; r += 8)
    out[(long)(n0 + r) * K + k0 + tx] = t[tx][r];
}

// ---- v[b][S][D] bf16 -> vT[b][D][S] bf16 ----
__global__ __launch_bounds__(256) void transpose_v(const u16* __restrict__ v,
                                                   u16* __restrict__ vt,
                                                   int S, int D) {
  __shared__ u16 t[32][33];
  long b = blockIdx.z;
  const u16* vb = v + b * S * D;
  u16* vtb = vt + b * S * D;
  int d0 = blockIdx.x * 32, s0 = blockIdx.y * 32;
  int tx = threadIdx.x & 31, ty = threadIdx.x >> 5;
  for (int r = ty; r < 32; r += 8)
    t[r][tx] = vb[(long)(s0 + r) * D + d0 + tx];
  __syncthreads();
  for (int r = ty; r < 32; r += 8)
    vtb[(long)(d0 + r) * S + s0 + tx] = t[tx][r];
}

// ---- shared 128x128 MFMA K-loop (BK=32), swizzled LDS ----
__device__ __forceinline__ void gemm_core(const u16* __restrict__ At,
                                          const u16* __restrict__ Bt,
                                          int lda, int ldb, int ktEnd,
                                          f32x4 (&acc)[4][4],
                                          u16* lA, u16* lB) {
  const int tid = threadIdx.x;
  const int lane = tid & 63, half = lane >> 4, l16 = lane & 15;
  const int wave = tid >> 6;
  const int wm = (wave >> 1) * 64, wn = (wave & 1) * 64;

  // staging: 512 chunks of 16B per matrix; LDS slot c holds global (row=c>>2,
  // kp=(c&3)^((c>>3)&3)).  Wave-contiguous dest (HW req for global_load_lds).
  const int c0 = tid, c1 = tid + 256;
  const int r0 = c0 >> 2, kp0 = (c0 & 3) ^ ((c0 >> 3) & 3);
  const int r1 = c1 >> 2, kp1 = (c1 & 3) ^ ((c1 >> 3) & 3);
  const u16* gA0 = At + (long)r0 * lda + kp0 * 8;
  const u16* gA1 = At + (long)r1 * lda + kp1 * 8;
  const u16* gB0 = Bt + (long)r0 * ldb + kp0 * 8;
  const u16* gB1 = Bt + (long)r1 * ldb + kp1 * 8;
  u16* lA0 = lA + c0 * 8; u16* lA1 = lA + c1 * 8;
  u16* lB0 = lB + c0 * 8; u16* lB1 = lB + c1 * 8;
  // fragment read swizzle: row=16a+l16 -> (row>>1)&3 == (l16>>1)&3, mi-invariant
  const int swz = (half ^ ((l16 >> 1) & 3)) * 8;

  for (int kt = 0; kt < ktEnd; ++kt) {
    const int k0 = kt * 32;
    gld_lds16(gA0 + k0, lA0);
    gld_lds16(gA1 + k0, lA1);
    gld_lds16(gB0 + k0, lB0);
    gld_lds16(gB1 + k0, lB1);
    __syncthreads();
    s16x8 af[4], bfr[4];
#pragma unroll
    for (int mi = 0; mi < 4; ++mi)
      af[mi] = *(const s16x8*)&lA[(wm + mi * 16 + l16) * 32 + swz];
#pragma unroll
    for (int ni = 0; ni < 4; ++ni)
      bfr[ni] = *(const s16x8*)&lB[(wn + ni * 16 + l16) * 32 + swz];
#pragma unroll
    for (int mi = 0; mi < 4; ++mi)
#pragma unroll
      for (int ni = 0; ni < 4; ++ni)
        acc[mi][ni] = __builtin_amdgcn_mfma_f32_16x16x32_bf16(af[mi], bfr[ni], acc[mi][ni], 0, 0, 0);
    __syncthreads();
  }
}

struct ProjPtrs {
  const u16* A[3];
  const u16* B[3];
  u16* C[3];
  const float* bias[3];
};

// ---- q/k/v projections, one dispatch (z = which projection) ----
__global__ __launch_bounds__(256, 2)
void gemm_proj(ProjPtrs p, int lda, int ldb, int ldc, int kTiles) {
  const int bn = blockIdx.x, bm = blockIdx.y, bz = blockIdx.z;
  __shared__ u16 lA[128 * 32], lB[128 * 32];
  f32x4 acc[4][4];
#pragma unroll
  for (int i = 0; i < 4; ++i)
#pragma unroll
    for (int j = 0; j < 4; ++j) { f32x4 z = {0.f, 0.f, 0.f, 0.f}; acc[i][j] = z; }

  gemm_core(p.A[bz] + (long)bm * 128 * lda, p.B[bz] + (long)bn * 128 * ldb,
            lda, ldb, kTiles, acc, lA, lB);

  const int lane = threadIdx.x & 63, half = lane >> 4, l16 = lane & 15;
  const int wave = threadIdx.x >> 6;
  const int wm = (wave >> 1) * 64, wn = (wave & 1) * 64;
  const int colBase = bn * 128 + wn + l16;
  const int rowBase = bm * 128 + wm + half * 4;
  u16* Cb = p.C[bz];
  const float* bias = p.bias[bz];
#pragma unroll
  for (int mi = 0; mi < 4; ++mi)
#pragma unroll
    for (int ni = 0; ni < 4; ++ni) {
      int col = colBase + ni * 16;
      float bv = bias[col];
#pragma unroll
      for (int r = 0; r < 4; ++r)
        Cb[(long)(rowBase + mi * 16 + r) * ldc + col] = f2bf(acc[mi][ni][r] + bv);
    }
}

// ---- scores = q k^T * scale, compact lower-triangular grid (x = tri index) ----
__global__ __launch_bounds__(256, 2)
void gemm_scores(const u16* __restrict__ q, const u16* __restrict__ k,
                 float* __restrict__ scores, int ld, long sQK, long sSC,
                 int kTiles, float scale) {
  const int t = blockIdx.x, bz = blockIdx.y;
  int bm = (int)((sqrtf(8.f * t + 1.f) - 1.f) * 0.5f);
  while ((bm + 1) * (bm + 2) / 2 <= t) ++bm;
  while (bm * (bm + 1) / 2 > t) --bm;
  const int bn = t - bm * (bm + 1) / 2;

  __shared__ u16 lA[128 * 32], lB[128 * 32];
  f32x4 acc[4][4];
#pragma unroll
  for (int i = 0; i < 4; ++i)
#pragma unroll
    for (int j = 0; j < 4; ++j) { f32x4 z = {0.f, 0.f, 0.f, 0.f}; acc[i][j] = z; }

  gemm_core(q + (long)bz * sQK + (long)bm * 128 * ld,
            k + (long)bz * sQK + (long)bn * 128 * ld,
            ld, ld, kTiles, acc, lA, lB);

  const int lane = threadIdx.x & 63, half = lane >> 4, l16 = lane & 15;
  const int wave = threadIdx.x >> 6;
  const int wm = (wave >> 1) * 64, wn = (wave & 1) * 64;
  float* Cb = scores + (long)bz * sSC;
  const int colBase = bn * 128 + wn + l16;
  const int rowBase = bm * 128 + wm + half * 4;
#pragma unroll
  for (int mi = 0; mi < 4; ++mi)
#pragma unroll
    for (int ni = 0; ni < 4; ++ni) {
      int col = colBase + ni * 16;
#pragma unroll
      for (int r = 0; r < 4; ++r)
        Cb[(long)(rowBase + mi * 16 + r) * 2048 + col] = acc[mi][ni][r] * scale;
    }
}

// ---- y = P v, K truncated at diagonal; heavy tiles (large bm) launch first ----
__global__ __launch_bounds__(256, 2)
void gemm_pv(const u16* __restrict__ P, const u16* __restrict__ vT,
             float* __restrict__ y, int lda, int ldb, int ldc,
             long sP, long sV, long sY, int kTiles) {
  const int bn = blockIdx.x, bz = blockIdx.z;
  const int bm = gridDim.y - 1 - blockIdx.y;   // heavy-first for packing
  int ktEnd = (bm + 1) * 4; if (ktEnd > kTiles) ktEnd = kTiles;

  __shared__ u16 lA[128 * 32], lB[128 * 32];
  f32x4 acc[4][4];
#pragma unroll
  for (int i = 0; i < 4; ++i)
#pragma unroll
    for (int j = 0; j < 4; ++j) { f32x4 z = {0.f, 0.f, 0.f, 0.f}; acc[i][j] = z; }

  gemm_core(P + (long)bz * sP + (long)bm * 128 * lda,
            vT + (long)bz * sV + (long)bn * 128 * ldb,
            lda, ldb, ktEnd, acc, lA, lB);

  const int lane = threadIdx.x & 63, half = lane >> 4, l16 = lane & 15;
  const int wave = threadIdx.x >> 6;
  const int wm = (wave >> 1) * 64, wn = (wave & 1) * 64;
  float* Cb = y + (long)bz * sY;
  const int colBase = bn * 128 + wn + l16;
  const int rowBase = bm * 128 + wm + half * 4;
#pragma unroll
  for (int mi = 0; mi < 4; ++mi)
#pragma unroll
    for (int ni = 0; ni < 4; ++ni) {
      int col = colBase + ni * 16;
#pragma unroll
      for (int r = 0; r < 4; ++r)
        Cb[(long)(rowBase + mi * 16 + r) * ldc + col] = acc[mi][ni][r];
    }
}

// ---- causal row softmax: scores f32 -> P bf16; zero only to 128-tile edge ----
__global__ __launch_bounds__(256) void softmax_causal(const float* __restrict__ scores,
                                                      u16* __restrict__ P, int S) {
  __shared__ float buf[2048];
  __shared__ float red[4];
  const int tid = threadIdx.x;
  const long row = blockIdx.x;       // b*S + i
  const int i = (int)(row & (S - 1));
  const int n = i + 1;
  const float* srow = scores + row * S;
  u16* prow = P + row * S;

  float m = -1e30f;
  for (int j = tid; j < n; j += 256) { float x = srow[j]; buf[j] = x; m = fmaxf(m, x); }
  for (int o = 32; o > 0; o >>= 1) m = fmaxf(m, __shfl_down(m, o));
  if ((tid & 63) == 0) red[tid >> 6] = m;
  __syncthreads();
  m = fmaxf(fmaxf(red[0], red[1]), fmaxf(red[2], red[3]));
  __syncthreads();
  float s = 0.f;
  for (int j = tid; j < n; j += 256) { float e = __expf(buf[j] - m); buf[j] = e; s += e; }
  for (int o = 32; o > 0; o >>= 1) s += __shfl_down(s, o);
  if ((tid & 63) == 0) red[tid >> 6] = s;
  __syncthreads();
  s = red[0] + red[1] + red[2] + red[3];
  float inv = 1.f / s;
  for (int j = tid; j < n; j += 256) prow[j] = f2bf(buf[j] * inv);
  const int zend = ((i >> 7) + 1) << 7;    // PV never reads past this tile edge
  for (int j = n + tid; j < zend; j += 256) prow[j] = 0;
}

extern "C" void kernel_launch(void* const* d_in, const int* in_sizes, int n_in,
                              void* d_out, int out_size, void* d_ws, size_t ws_size,
                              hipStream_t stream) {
  const int B = 8, S = 2048, DIN = 1024, DQ = 1024, DV = 1024;
  const long X  = (long)B * S * DIN;   // 16,777,216
  const long WN = (long)DIN * DQ;      //  1,048,576

  const float* query = (const float*)d_in[0];
  const float* key   = (const float*)d_in[1];
  const float* value = (const float*)d_in[2];
  const float* Wq = (const float*)d_in[3];
  const float* bq = (const float*)d_in[4];
  const float* Wk = (const float*)d_in[5];
  const float* bk = (const float*)d_in[6];
  const float* Wv = (const float*)d_in[7];
  const float* bv = (const float*)d_in[8];
  // d_in[9] = mask: deterministic causal triu -> never read.

  // workspace (u16 units), total 120,586,240 u16 = 241,172,480 B:
  //   [0,3X)           xq,xk,xv            dead after proj
  //   [3X,3X+3WN)      WqT,WkT,WvT         dead after proj
  //   [R1,R1+X)        vbuf                dead after transpose_v
  //   [R1+X,R1+2X)     q                   dead after scores
  //   [R1+2X,R1+3X)    k                   dead after scores
  //   [R1+3X,R1+4X)    vT                  dead after PV
  //   scores f32 (67.1M u16) aliases [0,R1+X) once x/W/vbuf are dead
  //   P (X u16) aliases q's slot once q,k are dead
  u16* w = (u16*)d_ws;
  u16* xq = w;                 // xk=+X, xv=+2X
  u16* WT = w + 3 * X;         // WqT, WkT, WvT (stride WN)
  const long R1 = 3 * X + 3 * WN;
  u16* vbuf = w + R1;
  u16* q  = w + R1 + X;
  u16* k  = w + R1 + 2 * X;
  u16* vT = w + R1 + 3 * X;
  float* scores = (float*)d_ws;
  u16* P = q;                  // alias

  dim3 blk(256);
  cvt_bf16_3<<<dim3(X / 1024, 3), blk, 0, stream>>>(query, key, value, xq, X);
  transpose_w3<<<dim3(DQ / 32, DIN / 32, 3), blk, 0, stream>>>(Wq, Wk, Wv, WT, DIN, DQ, WN);

  // projections: M=16384, N=1024, K=1024, z = {q,k,v}
  ProjPtrs pp;
  pp.A[0] = xq; pp.A[1] = xq + X; pp.A[2] = xq + 2 * X;
  pp.B[0] = WT; pp.B[1] = WT + WN; pp.B[2] = WT + 2 * WN;
  pp.C[0] = q;  pp.C[1] = k;      pp.C[2] = vbuf;
  pp.bias[0] = bq; pp.bias[1] = bk; pp.bias[2] = bv;
  gemm_proj<<<dim3(DQ / 128, (B * S) / 128, 3), blk, 0, stream>>>(
      pp, DIN, DIN, DQ, DIN / 32);

  transpose_v<<<dim3(DV / 32, S / 32, B), blk, 0, stream>>>(vbuf, vT, S, DV);

  // scores: compact lower-tri grid, 136 tiles/batch, uniform K=1024
  gemm_scores<<<dim3(136, B), blk, 0, stream>>>(
      q, k, scores, DQ, X / B, (long)S * S, DQ / 32, 0.03125f);

  softmax_causal<<<dim3(B * S), blk, 0, stream>>>(scores, P, S);

  // y = P v: K truncated at diagonal, heavy-first
  gemm_pv<<<dim3(DV / 128, S / 128, B), blk, 0, stream>>>(
      P, vT, (float*)d_out, S, S, DV, (long)S * S, (long)DV * S, (long)S * DV,
      S / 32);
}